// Round 1
// baseline (249.837 us; speedup 1.0000x reference)
//
#include <hip/hip_runtime.h>
#include <hip/hip_bf16.h>

// Problem constants: x [B=32, C=512, H=64, W=64] fp32
#define NB 32
#define NC 512
#define NH 64
#define NW 64
#define NHW (NH * NW)            // 4096
#define NTOT ((size_t)NB * NC * NHW)

// workspace float offsets
#define OFF_S1SUM 0                       // 16384  (b,c spatial sums)
#define OFF_F2SUM 16384                   // 131072 (b,hw channel sums)
#define OFF_BNST  147456                  // 2 (+2 pad)
#define OFF_F1SIG 147460                  // 16384
#define OFF_F2RAW 163844                  // 131072
#define ZERO_BYTES (147460 * 4)           // zero s1sum + f2sum + bnstats

// ---------------------------------------------------------------------------
// Kernel A: fused reductions. One read of x produces:
//   s1sum[b,c]  = sum over hw of x[b,c,:,:]
//   f2sum[b,hw] = sum over c  of x[b,:,hw]
// grid = 32 b * 8 cgroups(64ch) * 4 jchunks(1024) = 1024 blocks, 256 thr.
__global__ __launch_bounds__(256) void k_reduce(const float* __restrict__ x,
                                                float* __restrict__ s1sum,
                                                float* __restrict__ f2sum) {
  const int bid = blockIdx.x;
  const int jc = bid & 3;
  const int cg = (bid >> 2) & 7;
  const int b = bid >> 5;
  const int tid = threadIdx.x;
  const int lane = tid & 63;
  const int j0 = jc * 1024 + tid * 4;
  const float* xb = x + ((size_t)(b * NC + cg * 64)) * NHW + j0;
  float a0 = 0.f, a1 = 0.f, a2 = 0.f, a3 = 0.f;
  for (int c = 0; c < 64; ++c) {
    const float4 v = *reinterpret_cast<const float4*>(xb + (size_t)c * NHW);
    a0 += v.x; a1 += v.y; a2 += v.z; a3 += v.w;
    float s = (v.x + v.y) + (v.z + v.w);
#pragma unroll
    for (int off = 32; off > 0; off >>= 1) s += __shfl_down(s, off);
    if (lane == 0) atomicAdd(&s1sum[b * NC + cg * 64 + c], s);
  }
  float* p = f2sum + b * NHW + j0;
  atomicAdd(p + 0, a0);
  atomicAdd(p + 1, a1);
  atomicAdd(p + 2, a2);
  atomicAdd(p + 3, a3);
}

// ---------------------------------------------------------------------------
// Kernel B: ECA channel conv (k=5, pad=2) over channel means + sigmoid.
// f1sig[b,c] = sigmoid( sum_k w1[k] * mean_hw(x[b, c+k-2]) )
__global__ __launch_bounds__(256) void k_f1(const float* __restrict__ s1sum,
                                            const float* __restrict__ w1,
                                            float* __restrict__ f1sig) {
  const int idx = blockIdx.x * 256 + threadIdx.x;  // 16384
  const int b = idx >> 9;
  const int c = idx & 511;
  float acc = 0.f;
#pragma unroll
  for (int k = 0; k < 5; ++k) {
    const int cc = c + k - 2;
    if (cc >= 0 && cc < NC) acc += w1[k] * s1sum[b * NC + cc];
  }
  acc *= (1.0f / (float)NHW);
  f1sig[idx] = 1.0f / (1.0f + __expf(-acc));
}

// ---------------------------------------------------------------------------
// Kernel C: spatial attention map.
//   m[b,i,j] = f2sum[b,i,j] / 512   (channel mean)
//   f2h[b,i,j] = sum_{ic,k} m[b,ic,j+k-1] * wh[i,ic,k]
//   f2w[b,i,j] = sum_{ic,k} m[b,i+k-1,ic] * ww[j,ic,k]
//   f2raw = f2h + f2w; also accumulate BN sums (sum, sumsq) into bnstats.
// grid = 32 b * 4 rowgroups(16 rows) = 128 blocks, 256 thr (4 outputs each).
__global__ __launch_bounds__(256) void k_f2(const float* __restrict__ f2sum,
                                            const float* __restrict__ wh,
                                            const float* __restrict__ ww,
                                            float* __restrict__ f2raw,
                                            float* __restrict__ bnstats) {
  __shared__ float m[NH][NW];
  const int b = blockIdx.x >> 2;
  const int r0 = (blockIdx.x & 3) * 16;
  const int tid = threadIdx.x;
  const int lane = tid & 63;
  for (int t = tid; t < NHW; t += 256)
    m[t >> 6][t & 63] = f2sum[b * NHW + t] * (1.0f / (float)NC);
  __syncthreads();

  float lsum = 0.f, lsq = 0.f;
#pragma unroll
  for (int t = 0; t < 4; ++t) {
    const int o = t * 256 + tid;      // 0..1023
    const int i = r0 + (o >> 6);
    const int j = o & 63;
    float acc = 0.f;
    const float* whp = wh + i * (NH * 3);   // wave-uniform
    for (int ic = 0; ic < NH; ++ic) {
      const float m0 = (j > 0) ? m[ic][j - 1] : 0.f;
      const float m1 = m[ic][j];
      const float m2 = (j < 63) ? m[ic][j + 1] : 0.f;
      acc += whp[ic * 3 + 0] * m0 + whp[ic * 3 + 1] * m1 + whp[ic * 3 + 2] * m2;
    }
    const float* wwp = ww + j * (NW * 3);
    for (int ic = 0; ic < NW; ++ic) {
      const float m0 = (i > 0) ? m[i - 1][ic] : 0.f;
      const float m1 = m[i][ic];
      const float m2 = (i < 63) ? m[i + 1][ic] : 0.f;
      acc += wwp[ic * 3 + 0] * m0 + wwp[ic * 3 + 1] * m1 + wwp[ic * 3 + 2] * m2;
    }
    f2raw[b * NHW + (i << 6) + j] = acc;
    lsum += acc;
    lsq += acc * acc;
  }
#pragma unroll
  for (int off = 32; off > 0; off >>= 1) {
    lsum += __shfl_down(lsum, off);
    lsq += __shfl_down(lsq, off);
  }
  if (lane == 0) {
    atomicAdd(&bnstats[0], lsum);
    atomicAdd(&bnstats[1], lsq);
  }
}

// ---------------------------------------------------------------------------
// Kernel D: out = x * f1sig[b,c] * sigmoid(g*(f2-mu)*rs + beta)
__global__ __launch_bounds__(256) void k_out(const float* __restrict__ x,
                                             const float* __restrict__ f1sig,
                                             const float* __restrict__ f2raw,
                                             const float* __restrict__ bnstats,
                                             const float* __restrict__ gamma,
                                             const float* __restrict__ beta,
                                             float* __restrict__ out) {
  const float N = (float)(NB * NHW);
  const float mu = bnstats[0] / N;
  const float var = bnstats[1] / N - mu * mu;
  const float rs = rsqrtf(var + 1e-5f);
  const float g = gamma[0] * rs;
  const float bt = beta[0];

  const size_t total4 = NTOT / 4;  // 8388608 float4
  const size_t stride = (size_t)gridDim.x * blockDim.x;
  for (size_t v = (size_t)blockIdx.x * blockDim.x + threadIdx.x; v < total4;
       v += stride) {
    const int hw4 = (int)(v & 1023);         // float4 index within hw plane
    const int bc = (int)(v >> 10);
    const int b = bc >> 9;
    const float f1 = f1sig[bc];
    const float4 xv = reinterpret_cast<const float4*>(x)[v];
    const float4 fv =
        reinterpret_cast<const float4*>(f2raw)[(size_t)(b << 10) + hw4];
    float4 ov;
    ov.x = xv.x * f1 * (1.0f / (1.0f + __expf(-(g * (fv.x - mu) + bt))));
    ov.y = xv.y * f1 * (1.0f / (1.0f + __expf(-(g * (fv.y - mu) + bt))));
    ov.z = xv.z * f1 * (1.0f / (1.0f + __expf(-(g * (fv.z - mu) + bt))));
    ov.w = xv.w * f1 * (1.0f / (1.0f + __expf(-(g * (fv.w - mu) + bt))));
    reinterpret_cast<float4*>(out)[v] = ov;
  }
}

// ---------------------------------------------------------------------------
extern "C" void kernel_launch(void* const* d_in, const int* in_sizes, int n_in,
                              void* d_out, int out_size, void* d_ws,
                              size_t ws_size, hipStream_t stream) {
  const float* x = (const float*)d_in[0];
  const float* w1 = (const float*)d_in[1];
  const float* wh = (const float*)d_in[2];
  const float* ww = (const float*)d_in[3];
  const float* gamma = (const float*)d_in[4];
  const float* beta = (const float*)d_in[5];
  float* out = (float*)d_out;
  float* ws = (float*)d_ws;

  float* s1sum = ws + OFF_S1SUM;
  float* f2sum = ws + OFF_F2SUM;
  float* bnstats = ws + OFF_BNST;
  float* f1sig = ws + OFF_F1SIG;
  float* f2raw = ws + OFF_F2RAW;

  hipMemsetAsync(d_ws, 0, ZERO_BYTES, stream);

  k_reduce<<<NB * 8 * 4, 256, 0, stream>>>(x, s1sum, f2sum);
  k_f1<<<(NB * NC) / 256, 256, 0, stream>>>(s1sum, w1, f1sig);
  k_f2<<<NB * 4, 256, 0, stream>>>(f2sum, wh, ww, f2raw, bnstats);
  k_out<<<2048, 256, 0, stream>>>(x, f1sig, f2raw, bnstats, gamma, beta, out);
}

// Round 3
// 183.395 us; speedup vs baseline: 1.3623x; 1.3623x over previous
//
#include <hip/hip_runtime.h>

// x [B=32, C=512, H=64, W=64] fp32
#define NB 32
#define NC 512
#define NH 64
#define NW 64
#define NHW 4096
#define NTOT ((size_t)NB * NC * NHW)

typedef float f32x4 __attribute__((ext_vector_type(4)));

// workspace float offsets (all regions fully rewritten every launch; no memset needed)
#define OFF_S1PART 0              // [B][C][4jc]        = 65536
#define OFF_F2PART 65536          // [8cg][B][4096pix]  = 1048576
#define OFF_M      1114112        // [B][4096]          = 131072
#define OFF_F1SIG  1245184        // [B][C]             = 16384
#define OFF_F2RAW  1261568        // [B][4096]          = 131072
#define OFF_BNPART 1392640        // [256 blocks][2]    = 512
#define OFF_BNST   1393152        // 2

// ---------------------------------------------------------------------------
// Kernel A: single pass over x, atomic-free.
//   s1part[b,c,jc]   = sum over the jc-th 1024-pixel chunk of x[b,c,:]
//   f2part[cg,b,pix] = sum over the cg-th 64-channel group of x[b,:,pix]
// grid = 32 b * 8 cg * 4 jc = 1024 blocks, 256 thr (4 pixels/thread).
__global__ __launch_bounds__(256) void k_reduce(const float* __restrict__ x,
                                                float* __restrict__ s1part,
                                                float* __restrict__ f2part) {
  __shared__ float lds_s1[64][4];
  const int bid = blockIdx.x;
  const int jc = bid & 3;
  const int cg = (bid >> 2) & 7;
  const int b = bid >> 5;
  const int tid = threadIdx.x;
  const int lane = tid & 63;
  const int wv = tid >> 6;
  const int j0 = jc * 1024 + tid * 4;
  const float* xb = x + ((size_t)(b * NC + cg * 64)) * NHW + j0;
  float a0 = 0.f, a1 = 0.f, a2 = 0.f, a3 = 0.f;
  for (int c = 0; c < 64; ++c) {
    const f32x4 v = *reinterpret_cast<const f32x4*>(xb + (size_t)c * NHW);
    a0 += v.x; a1 += v.y; a2 += v.z; a3 += v.w;
    float s = (v.x + v.y) + (v.z + v.w);
#pragma unroll
    for (int off = 32; off > 0; off >>= 1) s += __shfl_down(s, off);
    if (lane == 0) lds_s1[c][wv] = s;
  }
  __syncthreads();
  if (tid < 64) {
    const float s =
        lds_s1[tid][0] + lds_s1[tid][1] + lds_s1[tid][2] + lds_s1[tid][3];
    s1part[(b * NC + cg * 64 + tid) * 4 + jc] = s;
  }
  f32x4 o;
  o.x = a0; o.y = a1; o.z = a2; o.w = a3;
  *reinterpret_cast<f32x4*>(f2part + ((size_t)cg * NB + b) * NHW + j0) = o;
}

// ---------------------------------------------------------------------------
// Kernel B: combine partials.
//   blocks [0,128):  m[b,pix] = sum_cg f2part[cg,b,pix] / 512   (float4/thread)
//   blocks [128,192): f1sig[b,c] = sigmoid(conv5(s1sum)/4096)
__global__ __launch_bounds__(256) void k_mid(const float* __restrict__ s1part,
                                             const float* __restrict__ f2part,
                                             const float* __restrict__ w1,
                                             float* __restrict__ m,
                                             float* __restrict__ f1sig) {
  const int gid = blockIdx.x * 256 + threadIdx.x;
  if (blockIdx.x < 128) {
    const int b = gid >> 10;
    const int p4 = gid & 1023;
    f32x4 acc = {0.f, 0.f, 0.f, 0.f};
#pragma unroll
    for (int cg = 0; cg < 8; ++cg) {
      const f32x4 v = reinterpret_cast<const f32x4*>(
          f2part + ((size_t)cg * NB + b) * NHW)[p4];
      acc += v;
    }
    acc *= (1.0f / (float)NC);
    reinterpret_cast<f32x4*>(m + (size_t)b * NHW)[p4] = acc;
  } else {
    const int idx = gid - 32768;  // [0,16384)
    const int b = idx >> 9;
    const int c = idx & 511;
    float acc = 0.f;
#pragma unroll
    for (int k = 0; k < 5; ++k) {
      const int cc = c + k - 2;
      if (cc >= 0 && cc < NC) {
        const f32x4 sp = reinterpret_cast<const f32x4*>(s1part)[b * NC + cc];
        acc += w1[k] * ((sp.x + sp.y) + (sp.z + sp.w));
      }
    }
    acc *= (1.0f / (float)NHW);
    f1sig[idx] = 1.0f / (1.0f + __expf(-acc));
  }
}

// ---------------------------------------------------------------------------
// Kernel C: spatial attention map, all operands in LDS.
//   f2raw[b,i,j] = sum_{ic,k} m[b,ic,j+k-1]*wh[i,ic,k] + m[b,i+k-1,ic]*ww[j,ic,k]
// grid = 32 b * 8 rowgroups(8 rows) = 256 blocks, 256 thr, 2 outputs/thread.
// LDS: halo-padded m (no edge branches), wh linear (reads are wave-uniform
// broadcasts), ww padded 192->201 (lane stride 201 -> 9 mod 32, coprime ->
// conflict-free). ~118 KB -> 1 block/CU.
__global__ __launch_bounds__(256) void k_f2(const float* __restrict__ m,
                                            const float* __restrict__ wh,
                                            const float* __restrict__ ww,
                                            float* __restrict__ f2raw,
                                            float* __restrict__ bnpart) {
  __shared__ float mp[66][66];
  __shared__ float whL[64 * 192];
  __shared__ float wwL[64][201];
  __shared__ float red[8];
  const int b = blockIdx.x >> 3;
  const int rg = blockIdx.x & 7;
  const int tid = threadIdx.x;
  for (int t = tid; t < 66 * 66; t += 256) (&mp[0][0])[t] = 0.f;
  __syncthreads();
  for (int t = tid; t < NHW; t += 256)
    mp[1 + (t >> 6)][1 + (t & 63)] = m[(size_t)b * NHW + t];
  for (int t = tid; t < 64 * 192; t += 256) whL[t] = wh[t];
  for (int t = tid; t < 64 * 192; t += 256) wwL[t / 192][t % 192] = ww[t];
  __syncthreads();

  float lsum = 0.f, lsq = 0.f;
#pragma unroll
  for (int t = 0; t < 2; ++t) {
    const int o = t * 256 + tid;
    const int i = rg * 8 + (o >> 6);  // wave-uniform
    const int j = o & 63;             // = lane
    float acc = 0.f;
    const float* whp = &whL[i * 192];
    for (int ic = 0; ic < 64; ++ic) {
      acc += whp[ic * 3 + 0] * mp[ic + 1][j] +
             whp[ic * 3 + 1] * mp[ic + 1][j + 1] +
             whp[ic * 3 + 2] * mp[ic + 1][j + 2];
    }
    const float* wwp = &wwL[j][0];
    for (int ic = 0; ic < 64; ++ic) {
      acc += wwp[ic * 3 + 0] * mp[i][ic + 1] +
             wwp[ic * 3 + 1] * mp[i + 1][ic + 1] +
             wwp[ic * 3 + 2] * mp[i + 2][ic + 1];
    }
    f2raw[(size_t)b * NHW + (i << 6) + j] = acc;
    lsum += acc;
    lsq += acc * acc;
  }
#pragma unroll
  for (int off = 32; off > 0; off >>= 1) {
    lsum += __shfl_down(lsum, off);
    lsq += __shfl_down(lsq, off);
  }
  if ((tid & 63) == 0) {
    red[(tid >> 6) * 2 + 0] = lsum;
    red[(tid >> 6) * 2 + 1] = lsq;
  }
  __syncthreads();
  if (tid == 0) {
    bnpart[blockIdx.x * 2 + 0] = red[0] + red[2] + red[4] + red[6];
    bnpart[blockIdx.x * 2 + 1] = red[1] + red[3] + red[5] + red[7];
  }
}

// ---------------------------------------------------------------------------
// Kernel C2: finalize BN stats (256 block-partials -> mu-num, sq-num).
__global__ __launch_bounds__(256) void k_bnfin(const float* __restrict__ bnpart,
                                               float* __restrict__ bnstats) {
  __shared__ float red[4][2];
  const int tid = threadIdx.x;
  float s = bnpart[tid * 2 + 0];
  float q = bnpart[tid * 2 + 1];
#pragma unroll
  for (int off = 32; off > 0; off >>= 1) {
    s += __shfl_down(s, off);
    q += __shfl_down(q, off);
  }
  if ((tid & 63) == 0) {
    red[tid >> 6][0] = s;
    red[tid >> 6][1] = q;
  }
  __syncthreads();
  if (tid == 0) {
    bnstats[0] = red[0][0] + red[1][0] + red[2][0] + red[3][0];
    bnstats[1] = red[0][1] + red[1][1] + red[2][1] + red[3][1];
  }
}

// ---------------------------------------------------------------------------
// Kernel D: out = x * f1sig[b,c] * sigmoid(g*(f2-mu)+beta).
// Nontemporal x-loads / out-stores: out is never re-read and this second x
// pass shouldn't evict the L3 copy established by k_reduce (x = 268 MB vs
// 256 MB L3 -> mostly resident).
__global__ __launch_bounds__(256) void k_out(const float* __restrict__ x,
                                             const float* __restrict__ f1sig,
                                             const float* __restrict__ f2raw,
                                             const float* __restrict__ bnstats,
                                             const float* __restrict__ gamma,
                                             const float* __restrict__ beta,
                                             float* __restrict__ out) {
  const float N = (float)(NB * NHW);
  const float mu = bnstats[0] / N;
  const float var = bnstats[1] / N - mu * mu;
  const float rs = rsqrtf(var + 1e-5f);
  const float g = gamma[0] * rs;
  const float bt = beta[0];

  const size_t total4 = NTOT / 4;
  const size_t stride = (size_t)gridDim.x * blockDim.x;
  for (size_t v = (size_t)blockIdx.x * blockDim.x + threadIdx.x; v < total4;
       v += stride) {
    const int hw4 = (int)(v & 1023);
    const int bc = (int)(v >> 10);
    const int b = bc >> 9;
    const float f1 = f1sig[bc];
    const f32x4 xv =
        __builtin_nontemporal_load(reinterpret_cast<const f32x4*>(x) + v);
    const f32x4 fv =
        reinterpret_cast<const f32x4*>(f2raw)[(size_t)(b << 10) + hw4];
    f32x4 ov;
    ov.x = xv.x * f1 * (1.0f / (1.0f + __expf(-(g * (fv.x - mu) + bt))));
    ov.y = xv.y * f1 * (1.0f / (1.0f + __expf(-(g * (fv.y - mu) + bt))));
    ov.z = xv.z * f1 * (1.0f / (1.0f + __expf(-(g * (fv.z - mu) + bt))));
    ov.w = xv.w * f1 * (1.0f / (1.0f + __expf(-(g * (fv.w - mu) + bt))));
    __builtin_nontemporal_store(ov, reinterpret_cast<f32x4*>(out) + v);
  }
}

// ---------------------------------------------------------------------------
extern "C" void kernel_launch(void* const* d_in, const int* in_sizes, int n_in,
                              void* d_out, int out_size, void* d_ws,
                              size_t ws_size, hipStream_t stream) {
  const float* x = (const float*)d_in[0];
  const float* w1 = (const float*)d_in[1];
  const float* wh = (const float*)d_in[2];
  const float* ww = (const float*)d_in[3];
  const float* gamma = (const float*)d_in[4];
  const float* beta = (const float*)d_in[5];
  float* out = (float*)d_out;
  float* ws = (float*)d_ws;

  float* s1part = ws + OFF_S1PART;
  float* f2part = ws + OFF_F2PART;
  float* m = ws + OFF_M;
  float* f1sig = ws + OFF_F1SIG;
  float* f2raw = ws + OFF_F2RAW;
  float* bnpart = ws + OFF_BNPART;
  float* bnstats = ws + OFF_BNST;

  k_reduce<<<NB * 8 * 4, 256, 0, stream>>>(x, s1part, f2part);
  k_mid<<<192, 256, 0, stream>>>(s1part, f2part, w1, m, f1sig);
  k_f2<<<NB * 8, 256, 0, stream>>>(m, wh, ww, f2raw, bnpart);
  k_bnfin<<<1, 256, 0, stream>>>(bnpart, bnstats);
  k_out<<<2048, 256, 0, stream>>>(x, f1sig, f2raw, bnstats, gamma, beta, out);
}

// Round 4
// 165.103 us; speedup vs baseline: 1.5132x; 1.1108x over previous
//
#include <hip/hip_runtime.h>

// x [B=32, C=512, H=64, W=64] fp32
#define NB 32
#define NC 512
#define NH 64
#define NW 64
#define NHW 4096
#define NTOT ((size_t)NB * NC * NHW)

typedef float f32x4 __attribute__((ext_vector_type(4)));

// workspace float offsets (every region fully rewritten each launch)
#define OFF_S1PART 0              // [B][C][4jc]        = 65536
#define OFF_F2PART 65536          // [8cg][B][4096pix]  = 1048576
#define OFF_F1SIG  1114112        // [B][C]             = 16384
#define OFF_F2RAW  1130496        // [B][4096]          = 131072
#define OFF_BNPART 1261568        // [512 blocks][2]    = 1024

// ---------------------------------------------------------------------------
// Kernel A: single pass over x, atomic-free.
//   s1part[b,c,jc]   = sum over the jc-th 1024-pixel chunk of x[b,c,:]
//   f2part[cg,b,pix] = sum over the cg-th 64-channel group of x[b,:,pix]
// grid = 32 b * 8 cg * 4 jc = 1024 blocks, 256 thr (4 pixels/thread).
__global__ __launch_bounds__(256) void k_reduce(const float* __restrict__ x,
                                                float* __restrict__ s1part,
                                                float* __restrict__ f2part) {
  __shared__ float lds_s1[64][4];
  const int bid = blockIdx.x;
  const int jc = bid & 3;
  const int cg = (bid >> 2) & 7;
  const int b = bid >> 5;
  const int tid = threadIdx.x;
  const int lane = tid & 63;
  const int wv = tid >> 6;
  const int j0 = jc * 1024 + tid * 4;
  const float* xb = x + ((size_t)(b * NC + cg * 64)) * NHW + j0;
  float a0 = 0.f, a1 = 0.f, a2 = 0.f, a3 = 0.f;
  for (int c = 0; c < 64; ++c) {
    const f32x4 v = *reinterpret_cast<const f32x4*>(xb + (size_t)c * NHW);
    a0 += v.x; a1 += v.y; a2 += v.z; a3 += v.w;
    float s = (v.x + v.y) + (v.z + v.w);
#pragma unroll
    for (int off = 32; off > 0; off >>= 1) s += __shfl_down(s, off);
    if (lane == 0) lds_s1[c][wv] = s;
  }
  __syncthreads();
  if (tid < 64) {
    const float s =
        lds_s1[tid][0] + lds_s1[tid][1] + lds_s1[tid][2] + lds_s1[tid][3];
    s1part[(b * NC + cg * 64 + tid) * 4 + jc] = s;
  }
  f32x4 o;
  o.x = a0; o.y = a1; o.z = a2; o.w = a3;
  *reinterpret_cast<f32x4*>(f2part + ((size_t)cg * NB + b) * NHW + j0) = o;
}

// ---------------------------------------------------------------------------
// Kernel B: spatial attention map + f1sig, fused.
//   m[r,c] = (1/512) * sum_cg f2part[cg,b,r*64+c]        (built in LDS, halo)
//   f2raw[b,i,j] = sum_{ic,k} m[ic,j+k-1]*wh[i,ic,k] + m[i+k-1,ic]*ww[j,ic,k]
//   bnpart[blk] = (sum, sumsq) over this block's 256 outputs
//   rg==0 blocks additionally: f1sig[b,c] = sigmoid(conv5(s1sum)/4096)
// grid = 32 b * 16 rowgroups(4 rows) = 512 blocks, 256 thr, 1 output/thread.
// LDS 68 KB -> 2 blocks/CU resident (8 waves/CU).
//   wh reads: wave-uniform (i per wave) -> scalar loads from L2.
//   wwT[ick][j]: lane-consecutive, 66-pad -> conflict-free.
//   mp reads: h-conv per-lane consecutive (2-way, free); w-conv broadcast.
__global__ __launch_bounds__(256) void k_f2(const float* __restrict__ f2part,
                                            const float* __restrict__ s1part,
                                            const float* __restrict__ w1,
                                            const float* __restrict__ wh,
                                            const float* __restrict__ ww,
                                            float* __restrict__ f2raw,
                                            float* __restrict__ bnpart,
                                            float* __restrict__ f1sig) {
  __shared__ float mp[66][66];
  __shared__ float wwT[192][66];
  __shared__ float red[8];
  const int b = blockIdx.x >> 4;
  const int rg = blockIdx.x & 15;
  const int tid = threadIdx.x;

  // zero halo border only (interior is fully overwritten below)
  if (tid < 66) {
    mp[0][tid] = 0.f;
    mp[65][tid] = 0.f;
    mp[tid][0] = 0.f;
    mp[tid][65] = 0.f;
  }
  // stage ww transposed: wwT[ick][j] = ww[j*192 + ick]
  for (int t = tid; t < 64 * 192; t += 256) wwT[t % 192][t / 192] = ww[t];
  // build channel-mean map with halo offset
  for (int t = tid; t < NHW; t += 256) {
    float s = 0.f;
#pragma unroll
    for (int cg = 0; cg < 8; ++cg)
      s += f2part[((size_t)(cg * NB + b)) * NHW + t];
    mp[1 + (t >> 6)][1 + (t & 63)] = s * (1.0f / (float)NC);
  }
  __syncthreads();

  const int i = rg * 4 + (tid >> 6);  // wave-uniform row
  const int j = tid & 63;             // lane = output column
  const float* whp = wh + 192 * __builtin_amdgcn_readfirstlane(i);
  float acc = 0.f;
#pragma unroll 16
  for (int ic = 0; ic < 64; ++ic) {
    acc += whp[ic * 3 + 0] * mp[ic + 1][j] +
           whp[ic * 3 + 1] * mp[ic + 1][j + 1] +
           whp[ic * 3 + 2] * mp[ic + 1][j + 2];
    acc += wwT[ic * 3 + 0][j] * mp[i][ic + 1] +
           wwT[ic * 3 + 1][j] * mp[i + 1][ic + 1] +
           wwT[ic * 3 + 2][j] * mp[i + 2][ic + 1];
  }
  f2raw[(size_t)b * NHW + (i << 6) + j] = acc;

  // BN partial sums for this block
  float lsum = acc, lsq = acc * acc;
#pragma unroll
  for (int off = 32; off > 0; off >>= 1) {
    lsum += __shfl_down(lsum, off);
    lsq += __shfl_down(lsq, off);
  }
  if ((tid & 63) == 0) {
    red[(tid >> 6) * 2 + 0] = lsum;
    red[(tid >> 6) * 2 + 1] = lsq;
  }
  __syncthreads();
  if (tid == 0) {
    bnpart[blockIdx.x * 2 + 0] = red[0] + red[2] + red[4] + red[6];
    bnpart[blockIdx.x * 2 + 1] = red[1] + red[3] + red[5] + red[7];
  }

  // ECA channel attention (one block per b does it)
  if (rg == 0) {
#pragma unroll
    for (int c0 = 0; c0 < 512; c0 += 256) {
      const int c = c0 + tid;
      float acc5 = 0.f;
#pragma unroll
      for (int k = 0; k < 5; ++k) {
        const int cc = c + k - 2;
        if (cc >= 0 && cc < NC) {
          const f32x4 sp = reinterpret_cast<const f32x4*>(s1part)[b * NC + cc];
          acc5 += w1[k] * ((sp.x + sp.y) + (sp.z + sp.w));
        }
      }
      acc5 *= (1.0f / (float)NHW);
      f1sig[b * NC + c] = 1.0f / (1.0f + __expf(-acc5));
    }
  }
}

// ---------------------------------------------------------------------------
// Kernel C: out = x * f1sig[b,c] * sigmoid(g*(f2-mu)+beta).
// BN finalize done inline by wave 0 of every block (reads 512 partial pairs).
__global__ __launch_bounds__(256) void k_out(const float* __restrict__ x,
                                             const float* __restrict__ f1sig,
                                             const float* __restrict__ f2raw,
                                             const float* __restrict__ bnpart,
                                             const float* __restrict__ gamma,
                                             const float* __restrict__ beta,
                                             float* __restrict__ out) {
  __shared__ float bnv[2];
  const int tid = threadIdx.x;
  if (tid < 64) {
    float s = 0.f, q = 0.f;
#pragma unroll
    for (int r = 0; r < 8; ++r) {
      s += bnpart[2 * (tid + 64 * r) + 0];
      q += bnpart[2 * (tid + 64 * r) + 1];
    }
#pragma unroll
    for (int off = 32; off > 0; off >>= 1) {
      s += __shfl_down(s, off);
      q += __shfl_down(q, off);
    }
    if (tid == 0) {
      const float N = (float)(NB * NHW);
      const float mu = s / N;
      const float var = q / N - mu * mu;
      bnv[0] = mu;
      bnv[1] = gamma[0] * rsqrtf(var + 1e-5f);
    }
  }
  __syncthreads();
  const float mu = bnv[0];
  const float g = bnv[1];
  const float bt = beta[0];

  const size_t total4 = NTOT / 4;
  const size_t stride = (size_t)gridDim.x * blockDim.x;
  for (size_t v = (size_t)blockIdx.x * blockDim.x + tid; v < total4;
       v += stride) {
    const int hw4 = (int)(v & 1023);
    const int bc = (int)(v >> 10);
    const int b = bc >> 9;
    const float f1 = f1sig[bc];
    const f32x4 xv = reinterpret_cast<const f32x4*>(x)[v];
    const f32x4 fv =
        reinterpret_cast<const f32x4*>(f2raw)[(size_t)(b << 10) + hw4];
    f32x4 ov;
    ov.x = xv.x * f1 * (1.0f / (1.0f + __expf(-(g * (fv.x - mu) + bt))));
    ov.y = xv.y * f1 * (1.0f / (1.0f + __expf(-(g * (fv.y - mu) + bt))));
    ov.z = xv.z * f1 * (1.0f / (1.0f + __expf(-(g * (fv.z - mu) + bt))));
    ov.w = xv.w * f1 * (1.0f / (1.0f + __expf(-(g * (fv.w - mu) + bt))));
    __builtin_nontemporal_store(ov, reinterpret_cast<f32x4*>(out) + v);
  }
}

// ---------------------------------------------------------------------------
extern "C" void kernel_launch(void* const* d_in, const int* in_sizes, int n_in,
                              void* d_out, int out_size, void* d_ws,
                              size_t ws_size, hipStream_t stream) {
  const float* x = (const float*)d_in[0];
  const float* w1 = (const float*)d_in[1];
  const float* wh = (const float*)d_in[2];
  const float* ww = (const float*)d_in[3];
  const float* gamma = (const float*)d_in[4];
  const float* beta = (const float*)d_in[5];
  float* out = (float*)d_out;
  float* ws = (float*)d_ws;

  float* s1part = ws + OFF_S1PART;
  float* f2part = ws + OFF_F2PART;
  float* f1sig = ws + OFF_F1SIG;
  float* f2raw = ws + OFF_F2RAW;
  float* bnpart = ws + OFF_BNPART;

  k_reduce<<<NB * 8 * 4, 256, 0, stream>>>(x, s1part, f2part);
  k_f2<<<NB * 16, 256, 0, stream>>>(f2part, s1part, w1, wh, ww, f2raw, bnpart,
                                    f1sig);
  k_out<<<2048, 256, 0, stream>>>(x, f1sig, f2raw, bnpart, gamma, beta, out);
}